// Round 7
// baseline (152.080 us; speedup 1.0000x reference)
//
#include <hip/hip_runtime.h>
#include <hip/hip_bf16.h>
#include <math.h>

typedef __bf16 bf16x8 __attribute__((ext_vector_type(8)));
typedef __bf16 bf16x4 __attribute__((ext_vector_type(4)));
typedef float  f32x4  __attribute__((ext_vector_type(4)));

constexpr int Nn = 8192;   // B*S
constexpr int Dd = 256;    // feature dim
constexpr float LOG2E     = 1.4426950408889634f;
constexpr float SIM_SCALE = 20.0f * LOG2E;   // (1/tau)*log2(e), tau=0.05
constexpr float SIM_BIAS  = -20.0f * LOG2E;  // fixed max = 1/tau (|q.k|<=1)

// ---------------------------------------------------------------------------
// Kernel 1: L2-normalize rows -> bf16; init cbias / g_all; adv = pad?ad:-1.
// ---------------------------------------------------------------------------
__global__ __launch_bounds__(256) void prep_kernel(const float* __restrict__ logits,
                                                   const float* __restrict__ labels,
                                                   const int* __restrict__ pad,
                                                   const int* __restrict__ ad,
                                                   __bf16* __restrict__ qb,
                                                   __bf16* __restrict__ kb,
                                                   float* __restrict__ cbias,
                                                   float* __restrict__ g_all,
                                                   int* __restrict__ adv) {
  const int j = blockIdx.x * 256 + threadIdx.x;
  if (j < Nn) {
    const int pj = pad[j];
    cbias[j] = pj ? 0.0f : -1e30f;
    g_all[j] = 0.0f;
    adv[j]   = pj ? ad[j] : -1;
  }

  const int gw   = (blockIdx.x * 256 + threadIdx.x) >> 6;
  const int lane = threadIdx.x & 63;
  const float* src;
  __bf16* dst;
  int row;
  if (gw < Nn) { src = logits; dst = qb; row = gw; }
  else         { src = labels; dst = kb; row = gw - Nn; }

  const float4 v = *reinterpret_cast<const float4*>(src + (size_t)row * Dd + lane * 4);
  float ss = v.x * v.x + v.y * v.y + v.z * v.z + v.w * v.w;
#pragma unroll
  for (int m = 32; m >= 1; m >>= 1) ss += __shfl_xor(ss, m);
  const float scale = 1.0f / fmaxf(sqrtf(ss), 1e-12f);

  bf16x4 o;
  o[0] = (__bf16)(v.x * scale);
  o[1] = (__bf16)(v.y * scale);
  o[2] = (__bf16)(v.z * scale);
  o[3] = (__bf16)(v.w * scale);
  *reinterpret_cast<bf16x4*>(dst + (size_t)row * Dd + lane * 4) = o;
}

// ---------------------------------------------------------------------------
// Kernel 2: sparse positive-sum. One wave per row: scan adv[] in 64-chunks
// (ballot), cooperative 64-lane dot per match (~8-16 matches/row), shfl
// reduce, exp, accumulate. Writes g_pos[row] directly (sole owner).
// ---------------------------------------------------------------------------
__global__ __launch_bounds__(256) void pos_kernel(const __bf16* __restrict__ qb,
                                                  const __bf16* __restrict__ kb,
                                                  const int* __restrict__ adv,
                                                  float* __restrict__ g_pos) {
  const int row  = (blockIdx.x * 256 + threadIdx.x) >> 6;
  const int lane = threadIdx.x & 63;
  const int myadv = adv[row];
  if (myadv < 0) {            // invalid row: excluded downstream; avoid -1==-1 scan blowup
    if (lane == 0) g_pos[row] = 1.0f;
    return;
  }

  const bf16x4 qv4 = *reinterpret_cast<const bf16x4*>(qb + (size_t)row * Dd + lane * 4);
  const float q0 = (float)qv4[0], q1 = (float)qv4[1], q2 = (float)qv4[2], q3 = (float)qv4[3];

  float p = 0.f;
  for (int base = 0; base < Nn; base += 64) {
    const unsigned long long mask = __ballot(adv[base + lane] == myadv);
    unsigned long long m = mask;
    while (m) {
      const int j = base + __ffsll(m) - 1;
      m &= m - 1;
      const bf16x4 kv4 = *reinterpret_cast<const bf16x4*>(kb + (size_t)j * Dd + lane * 4);
      float d = fmaf(q0, (float)kv4[0],
                fmaf(q1, (float)kv4[1],
                fmaf(q2, (float)kv4[2], q3 * (float)kv4[3])));
#pragma unroll
      for (int s = 32; s >= 1; s >>= 1) d += __shfl_xor(d, s);
      p += __builtin_amdgcn_exp2f(fmaf(d, SIM_SCALE, SIM_BIAS));
    }
  }
  if (lane == 0) g_pos[row] = p;
}

// ---------------------------------------------------------------------------
// Kernel 3: sim = Q K^T / tau + exp-sum-all epilogue (pos handled sparsely).
// K-loop identical to R4/R6 (0 conflicts): BK=64, XOR-swizzled LDS
// (group' = c ^ (row&7)), VGPR staging. Epilogue: 3 ops/entry
// (fma, v_exp_f32, add), single redA partial plane, atomicAdd g_all.
// ---------------------------------------------------------------------------
__global__ __launch_bounds__(256) void gemm_lse_kernel(const __bf16* __restrict__ qb,
                                                       const __bf16* __restrict__ kb,
                                                       const float* __restrict__ cbias,
                                                       float* __restrict__ g_all) {
  __shared__ __bf16 smem[2 * 128 * 64];  // 32 KiB: As | Bs, reused by epilogue
  __bf16* As = smem;
  __bf16* Bs = smem + 128 * 64;
  float* redA = reinterpret_cast<float*>(smem);  // 128 x 32 partials

  const int tid  = threadIdx.x;
  const int lane = tid & 63;
  const int w    = tid >> 6;
  const int wrow = (w >> 1) * 64;
  const int wcol = (w & 1) * 64;
  const int lq   = lane & 15;
  const int qd   = lane >> 4;
  const int rowBase = blockIdx.x * 128;
  const int colBase = blockIdx.y * 128;

  const int sr0 = tid >> 3;
  const int c0  = tid & 7;

  f32x4 c[4][4];
#pragma unroll
  for (int mt = 0; mt < 4; ++mt)
#pragma unroll
    for (int nt = 0; nt < 4; ++nt)
      c[mt][nt] = (f32x4){0.f, 0.f, 0.f, 0.f};

  for (int kk = 0; kk < 4; ++kk) {
    const int kOff = kk * 64;
    __syncthreads();
#pragma unroll
    for (int i = 0; i < 4; ++i) {
      const int sr  = sr0 + i * 32;
      const int dst = sr * 64 + (c0 ^ (sr & 7)) * 8;
      *reinterpret_cast<float4*>(&As[dst]) =
          *reinterpret_cast<const float4*>(qb + (size_t)(rowBase + sr) * Dd + kOff + c0 * 8);
      *reinterpret_cast<float4*>(&Bs[dst]) =
          *reinterpret_cast<const float4*>(kb + (size_t)(colBase + sr) * Dd + kOff + c0 * 8);
    }
    __syncthreads();

#pragma unroll
    for (int kq = 0; kq < 2; ++kq) {
      bf16x8 af[4], bfq[4];
      const int lg = kq * 4 + qd;
#pragma unroll
      for (int mt = 0; mt < 4; ++mt) {
        const int r = wrow + mt * 16 + lq;
        af[mt] = *reinterpret_cast<const bf16x8*>(&As[r * 64 + (lg ^ (r & 7)) * 8]);
      }
#pragma unroll
      for (int nt = 0; nt < 4; ++nt) {
        const int r = wcol + nt * 16 + lq;
        bfq[nt] = *reinterpret_cast<const bf16x8*>(&Bs[r * 64 + (lg ^ (r & 7)) * 8]);
      }
#pragma unroll
      for (int mt = 0; mt < 4; ++mt)
#pragma unroll
        for (int nt = 0; nt < 4; ++nt)
          c[mt][nt] = __builtin_amdgcn_mfma_f32_16x16x32_bf16(af[mt], bfq[nt], c[mt][nt], 0, 0, 0);
    }
  }

  // ---- epilogue: e = exp(sim - 20); invalid cols -> 0 via cbias = -1e30 ----
  float colB[4];
#pragma unroll
  for (int nt = 0; nt < 4; ++nt)
    colB[nt] = SIM_BIAS + cbias[colBase + wcol + nt * 16 + lq];

  __syncthreads();  // all waves done with As/Bs before reuse as partials

  const int idx = (w & 1) * 16 + lq;   // 32 partials per row
  const int g   = idx >> 2;
  const int gi  = idx & 3;

#pragma unroll
  for (int mt = 0; mt < 4; ++mt) {
#pragma unroll
    for (int r = 0; r < 4; ++r) {
      const int row = wrow + mt * 16 + qd * 4 + r;
      float a = 0.f;
#pragma unroll
      for (int nt = 0; nt < 4; ++nt)
        a += __builtin_amdgcn_exp2f(fmaf(c[mt][nt][r], SIM_SCALE, colB[nt]));
      redA[row * 32 + ((g ^ (row & 7)) << 2) + gi] = a;
    }
  }
  __syncthreads();

  if (tid < 128) {
    const int row = tid;
    float a = 0.f;
#pragma unroll
    for (int gg = 0; gg < 8; ++gg) {
      const f32x4 va = *reinterpret_cast<const f32x4*>(&redA[row * 32 + ((gg ^ (row & 7)) << 2)]);
      a += (va[0] + va[1]) + (va[2] + va[3]);
    }
    atomicAdd(&g_all[rowBase + row], a);
  }
}

// ---------------------------------------------------------------------------
// Kernel 4: loss = mean over valid rows of log(g_all) - log(g_pos).
// ---------------------------------------------------------------------------
__global__ __launch_bounds__(1024) void reduce_kernel(const float* __restrict__ g_all,
                                                      const float* __restrict__ g_pos,
                                                      const int* __restrict__ pad,
                                                      float* __restrict__ out) {
  __shared__ float sS[16], sC[16];
  const int t = threadIdx.x;
  float s = 0.f, c = 0.f;
  const float4* ga4 = (const float4*)g_all;
  const float4* gp4 = (const float4*)g_pos;
  const int4*   pd4 = (const int4*)pad;
  for (int i = t; i < Nn / 4; i += 1024) {
    const float4 ga = ga4[i];
    const float4 gp = gp4[i];
    const int4   pd = pd4[i];
    if (pd.x) { s += __logf(ga.x) - __logf(gp.x); c += 1.f; }
    if (pd.y) { s += __logf(ga.y) - __logf(gp.y); c += 1.f; }
    if (pd.z) { s += __logf(ga.z) - __logf(gp.z); c += 1.f; }
    if (pd.w) { s += __logf(ga.w) - __logf(gp.w); c += 1.f; }
  }
#pragma unroll
  for (int m = 32; m >= 1; m >>= 1) {
    s += __shfl_xor(s, m);
    c += __shfl_xor(c, m);
  }
  if ((t & 63) == 0) { sS[t >> 6] = s; sC[t >> 6] = c; }
  __syncthreads();
  if (t == 0) {
    float S = 0.f, C = 0.f;
#pragma unroll
    for (int i = 0; i < 16; ++i) { S += sS[i]; C += sC[i]; }
    out[0] = S / fmaxf(C, 1.0f);
  }
}

extern "C" void kernel_launch(void* const* d_in, const int* in_sizes, int n_in,
                              void* d_out, int out_size, void* d_ws, size_t ws_size,
                              hipStream_t stream) {
  const float* logits = (const float*)d_in[0];
  const float* labels = (const float*)d_in[1];
  const int*   pad    = (const int*)d_in[2];
  const int*   ad     = (const int*)d_in[3];

  char* ws = (char*)d_ws;
  __bf16* qb   = (__bf16*)(ws);                 // 4 MiB
  __bf16* kb   = (__bf16*)(ws + 4194304);       // 4 MiB
  float*  cb   = (float*)(ws + 8388608);        // 32 KiB
  float*  gAll = (float*)(ws + 8421376);        // 32 KiB
  float*  gPos = (float*)(ws + 8454144);        // 32 KiB
  int*    adv  = (int*)  (ws + 8486912);        // 32 KiB
  float*  out  = (float*)d_out;

  prep_kernel<<<4096, 256, 0, stream>>>(logits, labels, pad, ad, qb, kb, cb, gAll, adv);
  pos_kernel<<<2048, 256, 0, stream>>>(qb, kb, adv, gPos);
  gemm_lse_kernel<<<dim3(64, 64), 256, 0, stream>>>(qb, kb, cb, gAll);
  reduce_kernel<<<1, 1024, 0, stream>>>(gAll, gPos, pad, out);
}

// Round 8
// 145.071 us; speedup vs baseline: 1.0483x; 1.0483x over previous
//
#include <hip/hip_runtime.h>
#include <hip/hip_bf16.h>
#include <math.h>

typedef __bf16 bf16x8 __attribute__((ext_vector_type(8)));
typedef __bf16 bf16x4 __attribute__((ext_vector_type(4)));
typedef float  f32x4  __attribute__((ext_vector_type(4)));

constexpr int Nn = 8192;   // B*S
constexpr int Dd = 256;    // feature dim
constexpr int NG = 512;    // ad group slots (ad < 500)
constexpr int GB = 64;     // bucket capacity per group (expected ~8, Poisson-safe)
constexpr float LOG2E     = 1.4426950408889634f;
constexpr float SIM_SCALE = 20.0f * LOG2E;   // (1/tau)*log2(e), tau=0.05
constexpr float SIM_BIAS  = -20.0f * LOG2E;  // fixed max = 1/tau (|q.k|<=1)

// ---------------------------------------------------------------------------
// Kernel 1: L2-normalize rows -> bf16; init cbias / g_all; adv = pad?ad:-1;
// append valid rows to per-ad bucket lists (cnt pre-zeroed via memsetAsync).
// ---------------------------------------------------------------------------
__global__ __launch_bounds__(256) void prep_kernel(const float* __restrict__ logits,
                                                   const float* __restrict__ labels,
                                                   const int* __restrict__ pad,
                                                   const int* __restrict__ ad,
                                                   __bf16* __restrict__ qb,
                                                   __bf16* __restrict__ kb,
                                                   float* __restrict__ cbias,
                                                   float* __restrict__ g_all,
                                                   int* __restrict__ adv,
                                                   int* __restrict__ cnt,
                                                   int* __restrict__ bucket) {
  const int j = blockIdx.x * 256 + threadIdx.x;
  if (j < Nn) {
    const int pj = pad[j];
    cbias[j] = pj ? 0.0f : -1e30f;
    g_all[j] = 0.0f;
    const int a = pj ? ad[j] : -1;
    adv[j] = a;
    if (a >= 0) {
      const int pos = atomicAdd(&cnt[a], 1);
      if (pos < GB) bucket[a * GB + pos] = j;
    }
  }

  const int gw   = (blockIdx.x * 256 + threadIdx.x) >> 6;
  const int lane = threadIdx.x & 63;
  const float* src;
  __bf16* dst;
  int row;
  if (gw < Nn) { src = logits; dst = qb; row = gw; }
  else         { src = labels; dst = kb; row = gw - Nn; }

  const float4 v = *reinterpret_cast<const float4*>(src + (size_t)row * Dd + lane * 4);
  float ss = v.x * v.x + v.y * v.y + v.z * v.z + v.w * v.w;
#pragma unroll
  for (int m = 32; m >= 1; m >>= 1) ss += __shfl_xor(ss, m);
  const float scale = 1.0f / fmaxf(sqrtf(ss), 1e-12f);

  bf16x4 o;
  o[0] = (__bf16)(v.x * scale);
  o[1] = (__bf16)(v.y * scale);
  o[2] = (__bf16)(v.z * scale);
  o[3] = (__bf16)(v.w * scale);
  *reinterpret_cast<bf16x4*>(dst + (size_t)row * Dd + lane * 4) = o;
}

// ---------------------------------------------------------------------------
// Kernel 2: sparse positive-sum via bucket lists. One wave per row walks the
// ~8 members of its ad group: coalesced 512B kb-row read, cooperative dot,
// shfl reduce, exp. Sole owner of g_pos[row] -- no init/atomics needed.
// ---------------------------------------------------------------------------
__global__ __launch_bounds__(256) void pos_kernel(const __bf16* __restrict__ qb,
                                                  const __bf16* __restrict__ kb,
                                                  const int* __restrict__ adv,
                                                  const int* __restrict__ cnt,
                                                  const int* __restrict__ bucket,
                                                  float* __restrict__ g_pos) {
  const int row  = (blockIdx.x * 256 + threadIdx.x) >> 6;
  const int lane = threadIdx.x & 63;
  const int myadv = adv[row];
  if (myadv < 0) {            // invalid row: excluded downstream (pad check)
    if (lane == 0) g_pos[row] = 1.0f;
    return;
  }

  const bf16x4 qv4 = *reinterpret_cast<const bf16x4*>(qb + (size_t)row * Dd + lane * 4);
  const float q0 = (float)qv4[0], q1 = (float)qv4[1], q2 = (float)qv4[2], q3 = (float)qv4[3];

  const int n = min(cnt[myadv], GB);
  const int* bk = bucket + myadv * GB;

  float p = 0.f;
  for (int t = 0; t < n; ++t) {
    const int j = bk[t];
    const bf16x4 kv4 = *reinterpret_cast<const bf16x4*>(kb + (size_t)j * Dd + lane * 4);
    float d = fmaf(q0, (float)kv4[0],
              fmaf(q1, (float)kv4[1],
              fmaf(q2, (float)kv4[2], q3 * (float)kv4[3])));
#pragma unroll
    for (int s = 32; s >= 1; s >>= 1) d += __shfl_xor(d, s);
    p += __builtin_amdgcn_exp2f(fmaf(d, SIM_SCALE, SIM_BIAS));
  }
  if (lane == 0) g_pos[row] = p;
}

// ---------------------------------------------------------------------------
// Kernel 3: sim = Q K^T / tau + exp-sum-all epilogue (pos handled sparsely).
// Identical to R7 (53.3 us): BK=64, XOR-swizzled LDS (group' = c ^ (row&7)),
// VGPR staging, 3-op epilogue, LDS-transpose reduce, atomicAdd g_all.
// ---------------------------------------------------------------------------
__global__ __launch_bounds__(256) void gemm_lse_kernel(const __bf16* __restrict__ qb,
                                                       const __bf16* __restrict__ kb,
                                                       const float* __restrict__ cbias,
                                                       float* __restrict__ g_all) {
  __shared__ __bf16 smem[2 * 128 * 64];  // 32 KiB: As | Bs, reused by epilogue
  __bf16* As = smem;
  __bf16* Bs = smem + 128 * 64;
  float* redA = reinterpret_cast<float*>(smem);  // 128 x 32 partials

  const int tid  = threadIdx.x;
  const int lane = tid & 63;
  const int w    = tid >> 6;
  const int wrow = (w >> 1) * 64;
  const int wcol = (w & 1) * 64;
  const int lq   = lane & 15;
  const int qd   = lane >> 4;
  const int rowBase = blockIdx.x * 128;
  const int colBase = blockIdx.y * 128;

  const int sr0 = tid >> 3;
  const int c0  = tid & 7;

  f32x4 c[4][4];
#pragma unroll
  for (int mt = 0; mt < 4; ++mt)
#pragma unroll
    for (int nt = 0; nt < 4; ++nt)
      c[mt][nt] = (f32x4){0.f, 0.f, 0.f, 0.f};

  for (int kk = 0; kk < 4; ++kk) {
    const int kOff = kk * 64;
    __syncthreads();
#pragma unroll
    for (int i = 0; i < 4; ++i) {
      const int sr  = sr0 + i * 32;
      const int dst = sr * 64 + (c0 ^ (sr & 7)) * 8;
      *reinterpret_cast<float4*>(&As[dst]) =
          *reinterpret_cast<const float4*>(qb + (size_t)(rowBase + sr) * Dd + kOff + c0 * 8);
      *reinterpret_cast<float4*>(&Bs[dst]) =
          *reinterpret_cast<const float4*>(kb + (size_t)(colBase + sr) * Dd + kOff + c0 * 8);
    }
    __syncthreads();

#pragma unroll
    for (int kq = 0; kq < 2; ++kq) {
      bf16x8 af[4], bfq[4];
      const int lg = kq * 4 + qd;
#pragma unroll
      for (int mt = 0; mt < 4; ++mt) {
        const int r = wrow + mt * 16 + lq;
        af[mt] = *reinterpret_cast<const bf16x8*>(&As[r * 64 + (lg ^ (r & 7)) * 8]);
      }
#pragma unroll
      for (int nt = 0; nt < 4; ++nt) {
        const int r = wcol + nt * 16 + lq;
        bfq[nt] = *reinterpret_cast<const bf16x8*>(&Bs[r * 64 + (lg ^ (r & 7)) * 8]);
      }
#pragma unroll
      for (int mt = 0; mt < 4; ++mt)
#pragma unroll
        for (int nt = 0; nt < 4; ++nt)
          c[mt][nt] = __builtin_amdgcn_mfma_f32_16x16x32_bf16(af[mt], bfq[nt], c[mt][nt], 0, 0, 0);
    }
  }

  // ---- epilogue: e = exp(sim - 20); invalid cols -> 0 via cbias = -1e30 ----
  float colB[4];
#pragma unroll
  for (int nt = 0; nt < 4; ++nt)
    colB[nt] = SIM_BIAS + cbias[colBase + wcol + nt * 16 + lq];

  __syncthreads();  // all waves done with As/Bs before reuse as partials

  const int idx = (w & 1) * 16 + lq;   // 32 partials per row
  const int g   = idx >> 2;
  const int gi  = idx & 3;

#pragma unroll
  for (int mt = 0; mt < 4; ++mt) {
#pragma unroll
    for (int r = 0; r < 4; ++r) {
      const int row = wrow + mt * 16 + qd * 4 + r;
      float a = 0.f;
#pragma unroll
      for (int nt = 0; nt < 4; ++nt)
        a += __builtin_amdgcn_exp2f(fmaf(c[mt][nt][r], SIM_SCALE, colB[nt]));
      redA[row * 32 + ((g ^ (row & 7)) << 2) + gi] = a;
    }
  }
  __syncthreads();

  if (tid < 128) {
    const int row = tid;
    float a = 0.f;
#pragma unroll
    for (int gg = 0; gg < 8; ++gg) {
      const f32x4 va = *reinterpret_cast<const f32x4*>(&redA[row * 32 + ((gg ^ (row & 7)) << 2)]);
      a += (va[0] + va[1]) + (va[2] + va[3]);
    }
    atomicAdd(&g_all[rowBase + row], a);
  }
}

// ---------------------------------------------------------------------------
// Kernel 4: loss = mean over valid rows of log(g_all) - log(g_pos).
// ---------------------------------------------------------------------------
__global__ __launch_bounds__(1024) void reduce_kernel(const float* __restrict__ g_all,
                                                      const float* __restrict__ g_pos,
                                                      const int* __restrict__ pad,
                                                      float* __restrict__ out) {
  __shared__ float sS[16], sC[16];
  const int t = threadIdx.x;
  float s = 0.f, c = 0.f;
  const float4* ga4 = (const float4*)g_all;
  const float4* gp4 = (const float4*)g_pos;
  const int4*   pd4 = (const int4*)pad;
  for (int i = t; i < Nn / 4; i += 1024) {
    const float4 ga = ga4[i];
    const float4 gp = gp4[i];
    const int4   pd = pd4[i];
    if (pd.x) { s += __logf(ga.x) - __logf(gp.x); c += 1.f; }
    if (pd.y) { s += __logf(ga.y) - __logf(gp.y); c += 1.f; }
    if (pd.z) { s += __logf(ga.z) - __logf(gp.z); c += 1.f; }
    if (pd.w) { s += __logf(ga.w) - __logf(gp.w); c += 1.f; }
  }
#pragma unroll
  for (int m = 32; m >= 1; m >>= 1) {
    s += __shfl_xor(s, m);
    c += __shfl_xor(c, m);
  }
  if ((t & 63) == 0) { sS[t >> 6] = s; sC[t >> 6] = c; }
  __syncthreads();
  if (t == 0) {
    float S = 0.f, C = 0.f;
#pragma unroll
    for (int i = 0; i < 16; ++i) { S += sS[i]; C += sC[i]; }
    out[0] = S / fmaxf(C, 1.0f);
  }
}

extern "C" void kernel_launch(void* const* d_in, const int* in_sizes, int n_in,
                              void* d_out, int out_size, void* d_ws, size_t ws_size,
                              hipStream_t stream) {
  const float* logits = (const float*)d_in[0];
  const float* labels = (const float*)d_in[1];
  const int*   pad    = (const int*)d_in[2];
  const int*   ad     = (const int*)d_in[3];

  char* ws = (char*)d_ws;
  __bf16* qb    = (__bf16*)(ws);                 // 4 MiB
  __bf16* kb    = (__bf16*)(ws + 4194304);       // 4 MiB
  float*  cb    = (float*)(ws + 8388608);        // 32 KiB
  float*  gAll  = (float*)(ws + 8421376);        // 32 KiB
  float*  gPos  = (float*)(ws + 8454144);        // 32 KiB
  int*    adv   = (int*)  (ws + 8486912);        // 32 KiB
  int*    cnt   = (int*)  (ws + 8519680);        // 2 KiB
  int*    bkt   = (int*)  (ws + 8521728);        // 128 KiB
  float*  out   = (float*)d_out;

  hipMemsetAsync(cnt, 0, NG * sizeof(int), stream);
  prep_kernel<<<4096, 256, 0, stream>>>(logits, labels, pad, ad, qb, kb, cb, gAll, adv, cnt, bkt);
  pos_kernel<<<2048, 256, 0, stream>>>(qb, kb, adv, cnt, bkt, gPos);
  gemm_lse_kernel<<<dim3(64, 64), 256, 0, stream>>>(qb, kb, cb, gAll);
  reduce_kernel<<<1, 1024, 0, stream>>>(gAll, gPos, pad, out);
}